// Round 3
// baseline (6264.954 us; speedup 1.0000x reference)
//
#include <hip/hip_runtime.h>

#define B_ 256
#define T_ 512
#define I_ 64
#define H_ 512
#define O_ 16

typedef _Float16 half8 __attribute__((ext_vector_type(8)));
typedef _Float16 half4 __attribute__((ext_vector_type(4)));
typedef float    f32x4 __attribute__((ext_vector_type(4)));

#define MFMA16(a, b, c) __builtin_amdgcn_mfma_f32_16x16x32_f16((a), (b), (c), 0, 0, 0)

__device__ inline half8 cvt_h8(f32x4 a, f32x4 b) {
  half8 v;
  v[0] = (_Float16)a[0]; v[1] = (_Float16)a[1]; v[2] = (_Float16)a[2]; v[3] = (_Float16)a[3];
  v[4] = (_Float16)b[0]; v[5] = (_Float16)b[1]; v[6] = (_Float16)b[2]; v[7] = (_Float16)b[3];
  return v;
}

// Pairwise h-exchange buffers (double-buffered by step parity) + flags.
// Layout of each 16KB region: half8 slot S = (k>>3)*16 + n (B-frag order),
// k = 0..511 global, n = batch-in-group. Block (g,p) writes slots
// [p*512, p*512+512). Never read at t=0 (h0 path) -> no cross-launch reset
// needed. Flags ARE reset each launch (by xp_prepass, stream-ordered).
__device__ __attribute__((aligned(16))) _Float16 exch_g[2][16][1024 * 8]; // 512 KB
__device__ unsigned exch_flag[16][2][16];                                // 64B-padded

// ---------------- prepass: xp = W_ih @ x_t^T + b  (D-layout: col=batch, row=j) ----
// Stored f16 in consumer order: consumer GLOBAL thread tid_c = wglob*64+kq*16+n
// covers j = wglob*64 + ln*16 + 4kq + i, batch = g*16+n.
// Half-index = ((t*16+g)*512 + tid_c)*16 + ln*4 + i.
__global__ __launch_bounds__(256, 2)
void xp_prepass(const float* __restrict__ x, const float* __restrict__ W_ih,
                const float* __restrict__ b_ih, const float* __restrict__ b_hh,
                _Float16* __restrict__ xp) {
  const int tid = threadIdx.x, L = tid & 63, w = tid >> 6;
  const int n = L & 15, kq = (L >> 4) & 3;
  const int g = blockIdx.x & 15, tc = blockIdx.x >> 4;   // 512 blocks = 16 g x 32 tc

  // zero the pairwise flags for this launch (separate dispatch precedes rnn)
  if (blockIdx.x == 0) {
    unsigned* fl = (unsigned*)exch_flag;                 // 16*2*16 = 512 words
    fl[tid] = 0u; fl[tid + 256] = 0u;
  }

  __shared__ __attribute__((aligned(16))) _Float16 wlih[32 * 2 * 64 * 8]; // 64 KB A-frags
  __shared__ float biasl[512];
  const half8* wlih8 = (const half8*)wlih;

  #pragma unroll
  for (int u = 0; u < 16; ++u) {
    const int s = tid + u * 256;                 // [0,4096)
    const int jt = s >> 7, c = (s >> 6) & 1, Lp = s & 63;
    const int jl = Lp & 15, kq2 = Lp >> 4;
    const float* p = W_ih + (jt * 16 + jl) * I_ + c * 32 + kq2 * 8;
    ((half8*)wlih)[s] = cvt_h8(*(const f32x4*)(p), *(const f32x4*)(p + 4));
  }
  #pragma unroll
  for (int u = 0; u < 2; ++u) {
    const int idx = tid + u * 256;
    biasl[idx] = b_ih[idx] + b_hh[idx];
  }
  __syncthreads();

  half8 xb[4][2];
  #pragma unroll
  for (int rr = 0; rr < 4; ++rr) {
    const int t = tc * 16 + w * 4 + rr;
    const float* p = x + ((size_t)(g * 16 + n) * T_ + t) * I_ + kq * 8;
    xb[rr][0] = cvt_h8(*(const f32x4*)(p),      *(const f32x4*)(p + 4));
    xb[rr][1] = cvt_h8(*(const f32x4*)(p + 32), *(const f32x4*)(p + 36));
  }

  #pragma unroll 1
  for (int hi = 0; hi < 8; ++hi) {             // consumer global wave index
    half8 o[4][2];
    #pragma unroll
    for (int jt2 = 0; jt2 < 4; ++jt2) {
      const int jt = hi * 4 + jt2;
      const half8 a0 = wlih8[(jt * 2 + 0) * 64 + L];
      const half8 a1 = wlih8[(jt * 2 + 1) * 64 + L];
      const f32x4 bv = *(const f32x4*)&biasl[jt * 16 + 4 * kq];
      #pragma unroll
      for (int rr = 0; rr < 4; ++rr) {
        f32x4 acc; acc[0] = 0.f; acc[1] = 0.f; acc[2] = 0.f; acc[3] = 0.f;
        acc = MFMA16(a0, xb[rr][0], acc);
        acc = MFMA16(a1, xb[rr][1], acc);
        #pragma unroll
        for (int i = 0; i < 4; ++i)
          o[rr][jt2 >> 1][(jt2 & 1) * 4 + i] = (_Float16)(acc[i] + bv[i]);
      }
    }
    #pragma unroll
    for (int rr = 0; rr < 4; ++rr) {
      const int t = tc * 16 + w * 4 + rr;
      _Float16* dst = xp + ((size_t)(t * 16 + g) * 512 + hi * 64 + L) * 16;
      *(half8*)(dst)     = o[rr][0];
      *(half8*)(dst + 8) = o[rr][1];
    }
  }
}

// ---------------- main persistent RNN: CU-pair per batch-group ----------------
// 32 blocks x 256 threads (4 waves, 1 wave/SIMD -> 512 unified regs/wave).
// Block (g,p) owns j/k in [256p, 256p+256); its 4 waves own 64 j each.
// ALL 16 kc of W_hh for the wave's 64 j live in AGPRs (64 half8 = 256 AGPR;
// fits the 512 budget at 1 wave/SIMD -- round 2's spill was the 256-budget
// at 2 waves/SIMD). Per-step LDS: own-half h only (4 waves x 8 KB read +
// 8 KB write) vs 224 KB in the 8-wave structure. Peer half exchanged via
// L2-resident device-global buffer + pairwise release/acquire flags.
// Pairs (b, b+8) land on the same XCD under round-robin dispatch (heuristic
// only; correctness from agent-scope atomics).
__global__ __launch_bounds__(256, 1)
void rnn_persist(const float* __restrict__ h0, const float* __restrict__ W_hh,
                 const float* __restrict__ W_fc, const float* __restrict__ b_fc,
                 float* __restrict__ out, const _Float16* __restrict__ xp) {
  const int tid = threadIdx.x;     // 0..255
  const int L   = tid & 63;
  const int w   = tid >> 6;        // local wave 0..3
  const int n   = L & 15;
  const int kq  = (L >> 4) & 3;
  const int b   = blockIdx.x;
  const int g   = (b & 7) | ((b >> 4) << 3);   // batch group 0..15
  const int p   = (b >> 3) & 1;                // pair half
  const int jb  = p * 256;                     // own j/k base

  __shared__ __attribute__((aligned(16))) _Float16 hb[2 * 512 * 8];   // 16 KB (own half, dbuf)
  __shared__ float wfcf[16 * 513];                                    // 32.8 KB (FC epilogue)
  half8* hb8 = (half8*)hb;

  // ---- W_hh A-fragments, ALL resident in AGPRs ----
  // lane: j = jb + w*64 + ln*16 + n, k-run kq*8; kc-major: whR[kc*4+ln]
  half8 whR[64];   // 256 AGPR (class-pinned)
  #pragma unroll
  for (int kc = 0; kc < 16; ++kc) {
    #pragma unroll
    for (int ln = 0; ln < 4; ++ln) {
      const int j = jb + w * 64 + ln * 16 + n;
      const f32x4* pw = (const f32x4*)(W_hh + j * H_ + kc * 32 + kq * 8);
      whR[kc * 4 + ln] = cvt_h8(pw[0], pw[1]);
    }
  }
  #pragma unroll
  for (int i2 = 0; i2 < 64; ++i2) asm volatile("" : "+a"(whR[i2]));

  // ---- h(0) own half into buffer 0: local slot S = (k_local>>3)*16 + nb ----
  #pragma unroll
  for (int u = 0; u < 2; ++u) {
    const int S = tid + u * 256;                 // [0,512)
    const int k8l = S >> 4, nb = S & 15;
    const float* ph = h0 + (g * 16 + nb) * H_ + jb + k8l * 8;
    hb8[S] = cvt_h8(*(const f32x4*)(ph), *(const f32x4*)(ph + 4));
  }
  __syncthreads();

  // xp for t=0 (2 x half8 per thread; this block's half of the region)
  half8 xq0, xq1;
  {
    const half8* p0 = (const half8*)(xp + ((size_t)(0 * 16 + g) * 512 + jb + tid) * 16);
    xq0 = p0[0]; xq1 = p0[1];
  }

  const unsigned* pflag = &exch_flag[g][1 - p][0];
  unsigned* myflag = &exch_flag[g][p][0];

  #pragma unroll 1
  for (int t = 0; t < T_; ++t) {
    const half8* hbr = hb8 + (t & 1) * 512;
    half8* hbw = hb8 + ((t + 1) & 1) * 512;

    // acc init from xp
    f32x4 acc[4];
    #pragma unroll
    for (int ln = 0; ln < 4; ++ln)
      #pragma unroll
      for (int i = 0; i < 4; ++i)
        acc[ln][i] = (float)((ln < 2 ? xq0 : xq1)[(ln & 1) * 4 + i]);

    // prefetch xp for t+1 (in flight across the step)
    {
      const int tn = (t + 1) & (T_ - 1);
      const half8* pn = (const half8*)(xp + ((size_t)(tn * 16 + g) * 512 + jb + tid) * 16);
      xq0 = pn[0]; xq1 = pn[1];
    }

    // own-half B-frags from LDS (independent of peer -> overlaps the spin)
    half8 bf[16];
    #pragma unroll
    for (int c = 0; c < 8; ++c) bf[p * 8 + c] = hbr[c * 64 + L];

    // wait for peer h(t) (published with value t); t=0 comes from h0
    if (t > 0) {
      if (tid == 0) {
        while (__hip_atomic_load(pflag, __ATOMIC_ACQUIRE, __HIP_MEMORY_SCOPE_AGENT) < (unsigned)t)
          __builtin_amdgcn_s_sleep(1);
      }
      __syncthreads();
      const half8* eb = (const half8*)&exch_g[t & 1][g][0];
      #pragma unroll
      for (int c = 0; c < 8; ++c) {
        const int kcg = (1 - p) * 8 + c;
        bf[kcg] = eb[kcg * 64 + L];
      }
    } else {
      #pragma unroll
      for (int c = 0; c < 8; ++c) {
        const int kcg = (1 - p) * 8 + c;
        const float* ph = h0 + (g * 16 + n) * H_ + kcg * 32 + kq * 8;
        bf[kcg] = cvt_h8(*(const f32x4*)(ph), *(const f32x4*)(ph + 4));
      }
    }

    // MFMA wall: own kc first (LDS data ready), then peer kc (hides L2 latency)
    #pragma unroll
    for (int c = 0; c < 8; ++c) {
      const int kc = p * 8 + c;
      #pragma unroll
      for (int ln = 0; ln < 4; ++ln)
        acc[ln] = MFMA16(whR[kc * 4 + ln], bf[kc], acc[ln]);
    }
    #pragma unroll
    for (int c = 0; c < 8; ++c) {
      const int kc = (1 - p) * 8 + c;
      #pragma unroll
      for (int ln = 0; ln < 4; ++ln)
        acc[ln] = MFMA16(whR[kc * 4 + ln], bf[kc], acc[ln]);
    }

    // epilogue: relu -> own-half frags into LDS (self) and exch (peer).
    // thread covers j = jb + w*64 + ln*16 + 4kq + i, col n:
    // local k8l = 8w + 2ln + (kq>>1); slot Sl = k8l*16 + n; half-off 4*(kq&1)
    _Float16* ew = &exch_g[(t + 1) & 1][g][0];
    #pragma unroll
    for (int ln = 0; ln < 4; ++ln) {
      half4 hv;
      #pragma unroll
      for (int i = 0; i < 4; ++i) hv[i] = (_Float16)fmaxf(acc[ln][i], 0.f);
      const int Sl = (w * 8 + ln * 2 + (kq >> 1)) * 16 + n;
      *(half4*)((_Float16*)hbw + Sl * 8 + 4 * (kq & 1)) = hv;
      *(half4*)(ew + (p * 512 + Sl) * 8 + 4 * (kq & 1)) = hv;
    }
    __syncthreads();   // all waves' LDS+global stores drained (vmcnt before barrier)
    if (tid == 0)
      __hip_atomic_fetch_add(myflag, 1u, __ATOMIC_RELEASE, __HIP_MEMORY_SCOPE_AGENT);
  }

  // ---- output 1: h_last own half, fp32 at out+4096 (final h in buffer 0) ----
  const half8* hf = hb8;   // buffer 0 (T even)
  #pragma unroll
  for (int u = 0; u < 2; ++u) {
    const int ri = tid + u * 256;                 // [0,512)
    const int k8l = ri >> 4, nb = ri & 15;
    const half8 v = hf[ri];
    float* dst = out + 4096 + (g * 16 + nb) * H_ + jb + k8l * 8;
    #pragma unroll
    for (int e = 0; e < 8; ++e) dst[e] = (float)v[e];
  }

  // ---- output 0: FC, done by p==0 block using peer's final half ----
  if (p == 0) {
    if (tid == 0) {
      while (__hip_atomic_load(pflag, __ATOMIC_ACQUIRE, __HIP_MEMORY_SCOPE_AGENT) < (unsigned)T_)
        __builtin_amdgcn_s_sleep(1);
    }
    __syncthreads();
    // peer half (global slots 512..1023) into hb8[512..1024) -> full h in hb8
    {
      const half8* eb = (const half8*)&exch_g[T_ & 1][g][0];
      #pragma unroll
      for (int u = 0; u < 2; ++u) {
        const int S = tid + u * 256;
        hb8[512 + S] = eb[512 + S];
      }
    }
    #pragma unroll
    for (int u = 0; u < 32; ++u) {
      const int idx = tid + u * 256;
      wfcf[(idx >> 9) * 513 + (idx & 511)] = W_fc[idx];
    }
    __syncthreads();
    const int bl = tid >> 4, o = tid & 15;
    float s = 0.f;
    #pragma unroll 8
    for (int k8 = 0; k8 < 64; ++k8) {
      const half8 v = hb8[k8 * 16 + bl];
      #pragma unroll
      for (int e = 0; e < 8; ++e) s += (float)v[e] * wfcf[o * 513 + k8 * 8 + e];
    }
    out[(g * 16 + bl) * 16 + o] = s + b_fc[o];
  }
}

extern "C" void kernel_launch(void* const* d_in, const int* in_sizes, int n_in,
                              void* d_out, int out_size, void* d_ws, size_t ws_size,
                              hipStream_t stream) {
  const float* x    = (const float*)d_in[0];
  const float* h0   = (const float*)d_in[1];
  const float* W_ih = (const float*)d_in[2];
  const float* W_hh = (const float*)d_in[3];
  const float* b_ih = (const float*)d_in[4];
  const float* b_hh = (const float*)d_in[5];
  const float* W_fc = (const float*)d_in[6];
  const float* b_fc = (const float*)d_in[7];
  float* out = (float*)d_out;

  _Float16* xp = (_Float16*)d_ws;   // 128 MiB f16 workspace

  xp_prepass<<<dim3(512), dim3(256), 0, stream>>>(x, W_ih, b_ih, b_hh, xp);
  rnn_persist<<<dim3(32), dim3(256), 0, stream>>>(h0, W_hh, W_fc, b_fc, out, xp);
}

// Round 4
// 1264.643 us; speedup vs baseline: 4.9539x; 4.9539x over previous
//
#include <hip/hip_runtime.h>

#define B_ 256
#define T_ 512
#define I_ 64
#define H_ 512
#define O_ 16

typedef _Float16 half8 __attribute__((ext_vector_type(8)));
typedef _Float16 half4 __attribute__((ext_vector_type(4)));
typedef float    f32x4 __attribute__((ext_vector_type(4)));

#define MFMA16(a, b, c) __builtin_amdgcn_mfma_f32_16x16x32_f16((a), (b), (c), 0, 0, 0)

__device__ inline half8 cvt_h8(f32x4 a, f32x4 b) {
  half8 v;
  v[0] = (_Float16)a[0]; v[1] = (_Float16)a[1]; v[2] = (_Float16)a[2]; v[3] = (_Float16)a[3];
  v[4] = (_Float16)b[0]; v[5] = (_Float16)b[1]; v[6] = (_Float16)b[2]; v[7] = (_Float16)b[3];
  return v;
}

// ---------------- prepass: xp = W_ih @ x_t^T + b  (D-layout: col=batch, row=j) ----
// Stored f16 in EXACT consumer order for the 512-thread main kernel:
// consumer thread tid_c = w*64 + kq*16 + n covers j = w*64 + ln*16 + 4kq + i
// (ln 0..3), batch = g*16 + n. Half-index = ((t*16+g)*512 + tid_c)*16 + ln*4 + i.
__global__ __launch_bounds__(256, 2)
void xp_prepass(const float* __restrict__ x, const float* __restrict__ W_ih,
                const float* __restrict__ b_ih, const float* __restrict__ b_hh,
                _Float16* __restrict__ xp) {
  const int tid = threadIdx.x, L = tid & 63, w = tid >> 6;
  const int n = L & 15, kq = (L >> 4) & 3;
  const int g = blockIdx.x & 15, tc = blockIdx.x >> 4;   // 512 blocks = 16 g x 32 tc

  __shared__ __attribute__((aligned(16))) _Float16 wlih[32 * 2 * 64 * 8]; // 64 KB A-frags
  __shared__ float biasl[512];
  const half8* wlih8 = (const half8*)wlih;

  // stage W_ih as A-fragments: slot s = (jt*2+c)*64 + L'
  #pragma unroll
  for (int u = 0; u < 16; ++u) {
    const int s = tid + u * 256;                 // [0,4096)
    const int jt = s >> 7, c = (s >> 6) & 1, Lp = s & 63;
    const int jl = Lp & 15, kq2 = Lp >> 4;
    const float* p = W_ih + (jt * 16 + jl) * I_ + c * 32 + kq2 * 8;
    ((half8*)wlih)[s] = cvt_h8(*(const f32x4*)(p), *(const f32x4*)(p + 4));
  }
  #pragma unroll
  for (int u = 0; u < 2; ++u) {
    const int idx = tid + u * 256;
    biasl[idx] = b_ih[idx] + b_hh[idx];
  }
  __syncthreads();

  // x B-fragments for this wave's 4 timesteps
  half8 xb[4][2];
  #pragma unroll
  for (int rr = 0; rr < 4; ++rr) {
    const int t = tc * 16 + w * 4 + rr;
    const float* p = x + ((size_t)(g * 16 + n) * T_ + t) * I_ + kq * 8;
    xb[rr][0] = cvt_h8(*(const f32x4*)(p),      *(const f32x4*)(p + 4));
    xb[rr][1] = cvt_h8(*(const f32x4*)(p + 32), *(const f32x4*)(p + 36));
  }

  #pragma unroll 1
  for (int hi = 0; hi < 8; ++hi) {             // consumer wave index
    half8 o[4][2];                             // [rr][half of 16-half slot]
    #pragma unroll
    for (int jt2 = 0; jt2 < 4; ++jt2) {        // consumer ln
      const int jt = hi * 4 + jt2;
      const half8 a0 = wlih8[(jt * 2 + 0) * 64 + L];
      const half8 a1 = wlih8[(jt * 2 + 1) * 64 + L];
      const f32x4 bv = *(const f32x4*)&biasl[jt * 16 + 4 * kq];
      #pragma unroll
      for (int rr = 0; rr < 4; ++rr) {
        f32x4 acc; acc[0] = 0.f; acc[1] = 0.f; acc[2] = 0.f; acc[3] = 0.f;
        acc = MFMA16(a0, xb[rr][0], acc);
        acc = MFMA16(a1, xb[rr][1], acc);
        #pragma unroll
        for (int i = 0; i < 4; ++i)
          o[rr][jt2 >> 1][(jt2 & 1) * 4 + i] = (_Float16)(acc[i] + bv[i]);
      }
    }
    #pragma unroll
    for (int rr = 0; rr < 4; ++rr) {
      const int t = tc * 16 + w * 4 + rr;
      _Float16* dst = xp + ((size_t)(t * 16 + g) * 512 + hi * 64 + L) * 16;
      *(half8*)(dst)     = o[rr][0];
      *(half8*)(dst + 8) = o[rr][1];
    }
  }
}

// ---------------- main persistent RNN ----------------
// 16 blocks x 512 threads (8 waves, 2/SIMD, 256 unified regs/wave).
// Wave w owns j in [64w, 64w+64). W_hh: kc 0..7 AGPR-pinned (128), kc 8..11
// arch VGPR (64), kc 12..15 LDS (128 KB). h double-buffered in LDS B-frag
// layout (32 KB); LDS = 160 KB exactly. ONE barrier per step.
//
// Latency-hiding wall (this round's change): kc order interleaves the 4
// LDS-W kcs between AGPR kcs: {12,0,1,2,3,13,4,5,6,14,7,8,9,15,10,11}.
// B-frags rotate through bf[4] with reads issued 4 groups ahead (~58cy
// lead); LDS-W frags prefetch into wl[4] single-buffer with 4-5 group
// lead (~80cy). Targets the ds_read->MFMA latency stall (~1000cy/step in
// rounds 0/1, where rotation depth was 2 and wl reads had zero lead).
__global__ __launch_bounds__(512, 2)
void rnn_persist(const float* __restrict__ h0, const float* __restrict__ W_hh,
                 const float* __restrict__ W_fc, const float* __restrict__ b_fc,
                 float* __restrict__ out, const _Float16* __restrict__ xp) {
  const int tid = threadIdx.x;
  const int L   = tid & 63;
  const int w   = tid >> 6;        // wave 0..7
  const int n   = L & 15;          // batch col (B/D) or j-local (A)
  const int kq  = (L >> 4) & 3;
  const int g   = blockIdx.x;      // batches [16g, 16g+16)

  __shared__ __attribute__((aligned(16))) _Float16 hb[2 * 16 * 64 * 8];   // 32 KB
  __shared__ __attribute__((aligned(16))) _Float16 wlds[8 * 16 * 64 * 8]; // 128 KB
  half8* hb8 = (half8*)hb;
  const half8* wl8 = (const half8*)wlds;
  half8* wlw = (half8*)wlds;

  // ---- resident W_hh A-fragments (lane: j = w*64 + ln*16 + n, k-run kq*8) ----
  half8 whA[32];   // kc 0..7  -> 128 AGPR (class-pinned)
  half8 whV[16];   // kc 8..11 -> 64 arch VGPR
  #pragma unroll
  for (int kc = 0; kc < 8; ++kc)
    #pragma unroll
    for (int ln = 0; ln < 4; ++ln) {
      const int j = w * 64 + ln * 16 + n;
      const f32x4* p = (const f32x4*)(W_hh + j * H_ + kc * 32 + kq * 8);
      whA[kc * 4 + ln] = cvt_h8(p[0], p[1]);
    }
  #pragma unroll
  for (int kc = 8; kc < 12; ++kc)
    #pragma unroll
    for (int ln = 0; ln < 4; ++ln) {
      const int j = w * 64 + ln * 16 + n;
      const f32x4* p = (const f32x4*)(W_hh + j * H_ + kc * 32 + kq * 8);
      whV[(kc - 8) * 4 + ln] = cvt_h8(p[0], p[1]);
    }
  // kc 12..15 staged to LDS: 16 frags/wave, slot = (w*16 + (kc-12)*4 + ln)
  #pragma unroll
  for (int kc = 12; kc < 16; ++kc)
    #pragma unroll
    for (int ln = 0; ln < 4; ++ln) {
      const int j = w * 64 + ln * 16 + n;
      const f32x4* p = (const f32x4*)(W_hh + j * H_ + kc * 32 + kq * 8);
      wlw[(w * 16 + (kc - 12) * 4 + ln) * 64 + L] = cvt_h8(p[0], p[1]);
    }
  // One-time AGPR class pin for kc 0..7 (MFMAs stay builtins).
  #pragma unroll
  for (int i2 = 0; i2 < 32; ++i2) asm volatile("" : "+a"(whA[i2]));

  // ---- h(0) into B-layout buffer 0: half8 slot S = k8*16 + nb ----
  #pragma unroll
  for (int u = 0; u < 2; ++u) {
    const int S = tid + u * 512;                 // [0,1024)
    const int k8 = S >> 4, nb = S & 15;
    const float* p = h0 + (g * 16 + nb) * H_ + k8 * 8;
    hb8[S] = cvt_h8(*(const f32x4*)(p), *(const f32x4*)(p + 4));
  }
  __syncthreads();

  // xp for t=0 (2 x half8 per thread)
  half8 xq0, xq1;
  {
    const half8* p0 = (const half8*)(xp + ((size_t)(0 * 16 + g) * 512 + tid) * 16);
    xq0 = p0[0]; xq1 = p0[1];
  }

  // kc visit order: LDS-W kcs (12..15) spaced >=3 AGPR kcs apart
  // wl prefetch points: prologue->12, after idx0->13, after idx5->14, after idx9->15
  #pragma unroll 1
  for (int t = 0; t < T_; ++t) {
    const half8* hbr = hb8 + (t & 1) * 1024;
    half8* hbw = hb8 + ((t + 1) & 1) * 1024;

    // acc init from xp: acc[ln][i] for row j = w*64 + ln*16 + 4kq + i, col n
    f32x4 acc[4];
    #pragma unroll
    for (int ln = 0; ln < 4; ++ln)
      #pragma unroll
      for (int i = 0; i < 4; ++i)
        acc[ln][i] = (float)((ln < 2 ? xq0 : xq1)[(ln & 1) * 4 + i]);

    // prefetch xp for t+1 (in flight across the MFMA wall)
    {
      const int tn = (t + 1) & (T_ - 1);
      const half8* pn = (const half8*)(xp + ((size_t)(tn * 16 + g) * 512 + tid) * 16);
      xq0 = pn[0]; xq1 = pn[1];
    }

    constexpr int O[16] = {12,0,1,2,3,13,4,5,6,14,7,8,9,15,10,11};

    // prologue: wl <- kc12 frags; bf[0..3] <- h frags for O[0..3]
    half8 wl[4];
    #pragma unroll
    for (int ln = 0; ln < 4; ++ln) wl[ln] = wl8[(w * 16 + 0 * 4 + ln) * 64 + L];
    half8 bf[4];
    #pragma unroll
    for (int q = 0; q < 4; ++q) bf[q] = hbr[O[q] * 64 + L];

    #pragma unroll
    for (int i = 0; i < 16; ++i) {
      const int kc = O[i];
      // MFMA group for this kc
      if (kc < 8) {
        #pragma unroll
        for (int ln = 0; ln < 4; ++ln) acc[ln] = MFMA16(whA[kc * 4 + ln], bf[i & 3], acc[ln]);
      } else if (kc < 12) {
        #pragma unroll
        for (int ln = 0; ln < 4; ++ln) acc[ln] = MFMA16(whV[(kc - 8) * 4 + ln], bf[i & 3], acc[ln]);
      } else {
        #pragma unroll
        for (int ln = 0; ln < 4; ++ln) acc[ln] = MFMA16(wl[ln], bf[i & 3], acc[ln]);
      }
      // refill B-frag slot consumed this group (lead 4 groups)
      if (i < 12) bf[i & 3] = hbr[O[i + 4] * 64 + L];
      // wl prefetch: after consuming kc12/13/14, load the next LDS-W kc
      if (i == 0) {
        #pragma unroll
        for (int ln = 0; ln < 4; ++ln) wl[ln] = wl8[(w * 16 + 1 * 4 + ln) * 64 + L];
      } else if (i == 5) {
        #pragma unroll
        for (int ln = 0; ln < 4; ++ln) wl[ln] = wl8[(w * 16 + 2 * 4 + ln) * 64 + L];
      } else if (i == 9) {
        #pragma unroll
        for (int ln = 0; ln < 4; ++ln) wl[ln] = wl8[(w * 16 + 3 * 4 + ln) * 64 + L];
      }
    }

    // epilogue: relu -> b64 writes into next buffer.
    // thread covers j = w*64 + ln*16 + 4kq + i, col n:
    // half8 slot S = (w*8 + ln*2 + (kq>>1))*16 + n, half-offset 4*(kq&1)
    #pragma unroll
    for (int ln = 0; ln < 4; ++ln) {
      half4 hv;
      #pragma unroll
      for (int i = 0; i < 4; ++i) hv[i] = (_Float16)fmaxf(acc[ln][i], 0.f);
      const int S = (w * 8 + ln * 2 + (kq >> 1)) * 16 + n;
      *(half4*)((_Float16*)hbw + S * 8 + 4 * (kq & 1)) = hv;
    }
    __syncthreads();   // one barrier per step
  }

  // ---- output 1: h_last (1,B,H) fp32 at out+4096 (final h in buffer 0) ----
  const half8* hf = hb8;   // buffer 0 (T even)
  #pragma unroll
  for (int u = 0; u < 2; ++u) {
    const int ri = tid + u * 512;
    const int k8 = ri >> 4, nb = ri & 15;
    const half8 v = hf[k8 * 16 + nb];
    float* dst = out + 4096 + (g * 16 + nb) * H_ + k8 * 8;
    #pragma unroll
    for (int e = 0; e < 8; ++e) dst[e] = (float)v[e];
  }
  // ---- output 0: FC (reuse wlds as fp32 [16][513]) ----
  __syncthreads();
  float* wfcf = (float*)wlds;
  #pragma unroll
  for (int u = 0; u < 16; ++u) {
    const int idx = tid + u * 512;
    wfcf[(idx >> 9) * 513 + (idx & 511)] = W_fc[idx];
  }
  __syncthreads();
  if (tid < 256) {
    const int bl = tid >> 4, o = tid & 15;
    float s = 0.f;
    #pragma unroll 8
    for (int k8 = 0; k8 < 64; ++k8) {
      const half8 v = hf[k8 * 16 + bl];
      #pragma unroll
      for (int e = 0; e < 8; ++e) s += (float)v[e] * wfcf[o * 513 + k8 * 8 + e];
    }
    out[(g * 16 + bl) * 16 + o] = s + b_fc[o];
  }
}

extern "C" void kernel_launch(void* const* d_in, const int* in_sizes, int n_in,
                              void* d_out, int out_size, void* d_ws, size_t ws_size,
                              hipStream_t stream) {
  const float* x    = (const float*)d_in[0];
  const float* h0   = (const float*)d_in[1];
  const float* W_ih = (const float*)d_in[2];
  const float* W_hh = (const float*)d_in[3];
  const float* b_ih = (const float*)d_in[4];
  const float* b_hh = (const float*)d_in[5];
  const float* W_fc = (const float*)d_in[6];
  const float* b_fc = (const float*)d_in[7];
  float* out = (float*)d_out;

  _Float16* xp = (_Float16*)d_ws;   // 134 MB f16 workspace

  xp_prepass<<<dim3(512), dim3(256), 0, stream>>>(x, W_ih, b_ih, b_hh, xp);
  rnn_persist<<<dim3(16), dim3(512), 0, stream>>>(h0, W_hh, W_fc, b_fc, out, xp);
}

// Round 5
// 1063.451 us; speedup vs baseline: 5.8912x; 1.1892x over previous
//
#include <hip/hip_runtime.h>

#define B_ 256
#define T_ 512
#define I_ 64
#define H_ 512
#define O_ 16

typedef _Float16 half8 __attribute__((ext_vector_type(8)));
typedef _Float16 half4 __attribute__((ext_vector_type(4)));
typedef float    f32x4 __attribute__((ext_vector_type(4)));

#define MFMA16(a, b, c) __builtin_amdgcn_mfma_f32_16x16x32_f16((a), (b), (c), 0, 0, 0)

__device__ inline half8 cvt_h8(f32x4 a, f32x4 b) {
  half8 v;
  v[0] = (_Float16)a[0]; v[1] = (_Float16)a[1]; v[2] = (_Float16)a[2]; v[3] = (_Float16)a[3];
  v[4] = (_Float16)b[0]; v[5] = (_Float16)b[1]; v[6] = (_Float16)b[2]; v[7] = (_Float16)b[3];
  return v;
}

// ---------------- prepass: xp = W_ih @ x_t^T + b  (D-layout: col=batch, row=j) ----
// Stored f16 in EXACT consumer order for the 512-thread main kernel:
// consumer thread tid_c = w*64 + kq*16 + n covers j = w*64 + ln*16 + 4kq + i
// (ln 0..3), batch = g*16 + n. Half-index = ((t*16+g)*512 + tid_c)*16 + ln*4 + i.
__global__ __launch_bounds__(256, 2)
void xp_prepass(const float* __restrict__ x, const float* __restrict__ W_ih,
                const float* __restrict__ b_ih, const float* __restrict__ b_hh,
                _Float16* __restrict__ xp) {
  const int tid = threadIdx.x, L = tid & 63, w = tid >> 6;
  const int n = L & 15, kq = (L >> 4) & 3;
  const int g = blockIdx.x & 15, tc = blockIdx.x >> 4;   // 512 blocks = 16 g x 32 tc

  __shared__ __attribute__((aligned(16))) _Float16 wlih[32 * 2 * 64 * 8]; // 64 KB A-frags
  __shared__ float biasl[512];
  const half8* wlih8 = (const half8*)wlih;

  // stage W_ih as A-fragments: slot s = (jt*2+c)*64 + L'
  #pragma unroll
  for (int u = 0; u < 16; ++u) {
    const int s = tid + u * 256;                 // [0,4096)
    const int jt = s >> 7, c = (s >> 6) & 1, Lp = s & 63;
    const int jl = Lp & 15, kq2 = Lp >> 4;
    const float* p = W_ih + (jt * 16 + jl) * I_ + c * 32 + kq2 * 8;
    ((half8*)wlih)[s] = cvt_h8(*(const f32x4*)(p), *(const f32x4*)(p + 4));
  }
  #pragma unroll
  for (int u = 0; u < 2; ++u) {
    const int idx = tid + u * 256;
    biasl[idx] = b_ih[idx] + b_hh[idx];
  }
  __syncthreads();

  // x B-fragments for this wave's 4 timesteps
  half8 xb[4][2];
  #pragma unroll
  for (int rr = 0; rr < 4; ++rr) {
    const int t = tc * 16 + w * 4 + rr;
    const float* p = x + ((size_t)(g * 16 + n) * T_ + t) * I_ + kq * 8;
    xb[rr][0] = cvt_h8(*(const f32x4*)(p),      *(const f32x4*)(p + 4));
    xb[rr][1] = cvt_h8(*(const f32x4*)(p + 32), *(const f32x4*)(p + 36));
  }

  #pragma unroll 1
  for (int hi = 0; hi < 8; ++hi) {             // consumer wave index
    half8 o[4][2];                             // [rr][half of 16-half slot]
    #pragma unroll
    for (int jt2 = 0; jt2 < 4; ++jt2) {        // consumer ln
      const int jt = hi * 4 + jt2;
      const half8 a0 = wlih8[(jt * 2 + 0) * 64 + L];
      const half8 a1 = wlih8[(jt * 2 + 1) * 64 + L];
      const f32x4 bv = *(const f32x4*)&biasl[jt * 16 + 4 * kq];
      #pragma unroll
      for (int rr = 0; rr < 4; ++rr) {
        f32x4 acc; acc[0] = 0.f; acc[1] = 0.f; acc[2] = 0.f; acc[3] = 0.f;
        acc = MFMA16(a0, xb[rr][0], acc);
        acc = MFMA16(a1, xb[rr][1], acc);
        #pragma unroll
        for (int i = 0; i < 4; ++i)
          o[rr][jt2 >> 1][(jt2 & 1) * 4 + i] = (_Float16)(acc[i] + bv[i]);
      }
    }
    #pragma unroll
    for (int rr = 0; rr < 4; ++rr) {
      const int t = tc * 16 + w * 4 + rr;
      _Float16* dst = xp + ((size_t)(t * 16 + g) * 512 + hi * 64 + L) * 16;
      *(half8*)(dst)     = o[rr][0];
      *(half8*)(dst + 8) = o[rr][1];
    }
  }
}

// ---------------- main persistent RNN ----------------
// 16 blocks x 512 threads (8 waves, 2/SIMD, 256 unified regs/wave).
// Round-1 resource layout (proven spill-free): W_hh kc 0..11 AGPR-pinned
// (192), kc 12..15 LDS (128 KB); h double-buffered B-frag LDS (32 KB);
// LDS = 160 KB; ONE barrier per step. NO whV arch block (round 4's spill).
//
// This round: latency-hiding wall within the arch budget (~64 regs).
// kc order {12,0,1,2, 13,3,4,5, 14,6,7,8, 15,9,10,11}; wl[4] reloaded 4
// groups (~76cy) before use; the kc12 reload for step t+1 issues BEFORE
// the barrier (wlds is static after init -> race-free), lead ~400cy.
// b-rotation depth 2. Marginal evidence r0->r1 (+32KB LDS = +107cy only)
// says LDS pipe has slack -> stalls are ds_read->MFMA latency, chiefly the
// zero-lead wl reads (4 x ~100cy/step in round 1).
__global__ __launch_bounds__(512, 2)
void rnn_persist(const float* __restrict__ h0, const float* __restrict__ W_hh,
                 const float* __restrict__ W_fc, const float* __restrict__ b_fc,
                 float* __restrict__ out, const _Float16* __restrict__ xp) {
  const int tid = threadIdx.x;
  const int L   = tid & 63;
  const int w   = tid >> 6;        // wave 0..7
  const int n   = L & 15;          // batch col (B/D) or j-local (A)
  const int kq  = (L >> 4) & 3;
  const int g   = blockIdx.x;      // batches [16g, 16g+16)

  __shared__ __attribute__((aligned(16))) _Float16 hb[2 * 16 * 64 * 8];   // 32 KB
  __shared__ __attribute__((aligned(16))) _Float16 wlds[8 * 16 * 64 * 8]; // 128 KB
  half8* hb8 = (half8*)hb;
  const half8* wl8 = (const half8*)wlds;
  half8* wlw = (half8*)wlds;

  // ---- resident W_hh A-fragments (lane: j = w*64 + ln*16 + n, k-run kq*8) ----
  half8 whR[48];   // kc 0..11 -> 192 AGPR (class-pinned), kc-major
  #pragma unroll
  for (int kc = 0; kc < 12; ++kc)
    #pragma unroll
    for (int ln = 0; ln < 4; ++ln) {
      const int j = w * 64 + ln * 16 + n;
      const f32x4* p = (const f32x4*)(W_hh + j * H_ + kc * 32 + kq * 8);
      whR[kc * 4 + ln] = cvt_h8(p[0], p[1]);
    }
  // kc 12..15 staged to LDS: slot = (w*16 + (kc-12)*4 + ln)
  #pragma unroll
  for (int kc = 12; kc < 16; ++kc)
    #pragma unroll
    for (int ln = 0; ln < 4; ++ln) {
      const int j = w * 64 + ln * 16 + n;
      const f32x4* p = (const f32x4*)(W_hh + j * H_ + kc * 32 + kq * 8);
      wlw[(w * 16 + (kc - 12) * 4 + ln) * 64 + L] = cvt_h8(p[0], p[1]);
    }
  // One-time AGPR class pin (MFMAs stay builtins; hazards compiler-handled).
  #pragma unroll
  for (int i2 = 0; i2 < 48; ++i2) asm volatile("" : "+a"(whR[i2]));

  // ---- h(0) into B-layout buffer 0: half8 slot S = k8*16 + nb ----
  #pragma unroll
  for (int u = 0; u < 2; ++u) {
    const int S = tid + u * 512;                 // [0,1024)
    const int k8 = S >> 4, nb = S & 15;
    const float* p = h0 + (g * 16 + nb) * H_ + k8 * 8;
    hb8[S] = cvt_h8(*(const f32x4*)(p), *(const f32x4*)(p + 4));
  }
  __syncthreads();

  // xp for t=0 (2 x half8 per thread)
  half8 xq0, xq1;
  {
    const half8* p0 = (const half8*)(xp + ((size_t)(0 * 16 + g) * 512 + tid) * 16);
    xq0 = p0[0]; xq1 = p0[1];
  }

  // wl prologue: kc12 fragments (consumed first in each step's wall)
  half8 wl[4];
  #pragma unroll
  for (int ln = 0; ln < 4; ++ln) wl[ln] = wl8[(w * 16 + 0 * 4 + ln) * 64 + L];

  #pragma unroll 1
  for (int t = 0; t < T_; ++t) {
    const half8* hbr = hb8 + (t & 1) * 1024;
    half8* hbw = hb8 + ((t + 1) & 1) * 1024;

    // acc init from xp: acc[ln][i] for row j = w*64 + ln*16 + 4kq + i, col n
    f32x4 acc[4];
    #pragma unroll
    for (int ln = 0; ln < 4; ++ln)
      #pragma unroll
      for (int i = 0; i < 4; ++i)
        acc[ln][i] = (float)((ln < 2 ? xq0 : xq1)[(ln & 1) * 4 + i]);

    // prefetch xp for t+1 (in flight across the MFMA wall)
    {
      const int tn = (t + 1) & (T_ - 1);
      const half8* pn = (const half8*)(xp + ((size_t)(tn * 16 + g) * 512 + tid) * 16);
      xq0 = pn[0]; xq1 = pn[1];
    }

    // wall: LDS-W kcs spaced 4 apart; wl reloaded 4 groups ahead of use.
    constexpr int O[16] = {12,0,1,2, 13,3,4,5, 14,6,7,8, 15,9,10,11};

    half8 b0 = hbr[O[0] * 64 + L];
    half8 bn = hbr[O[1] * 64 + L];
    #pragma unroll
    for (int i = 0; i < 16; ++i) {
      const int kc = O[i];
      if (kc < 12) {
        #pragma unroll
        for (int ln = 0; ln < 4; ++ln) acc[ln] = MFMA16(whR[kc * 4 + ln], b0, acc[ln]);
      } else {
        #pragma unroll
        for (int ln = 0; ln < 4; ++ln) acc[ln] = MFMA16(wl[ln], b0, acc[ln]);
        // reload wl for the next LDS-W kc, 4 groups ahead of its use.
        // i==12 loads kc12 for the NEXT step (wlds static after init ->
        // safe to issue before the barrier; drained by the barrier's
        // lgkmcnt(0)).
        const int snext = (i == 0) ? 1 : (i == 4) ? 2 : (i == 8) ? 3 : 0;
        #pragma unroll
        for (int ln = 0; ln < 4; ++ln) wl[ln] = wl8[(w * 16 + snext * 4 + ln) * 64 + L];
      }
      // rotate B-frags: read 1 group ahead
      b0 = bn;
      if (i < 14) bn = hbr[O[i + 2] * 64 + L];
    }

    // epilogue: relu -> b64 writes into next buffer.
    // thread covers j = w*64 + ln*16 + 4kq + i, col n:
    // half8 slot S = (w*8 + ln*2 + (kq>>1))*16 + n, half-offset 4*(kq&1)
    #pragma unroll
    for (int ln = 0; ln < 4; ++ln) {
      half4 hv;
      #pragma unroll
      for (int i = 0; i < 4; ++i) hv[i] = (_Float16)fmaxf(acc[ln][i], 0.f);
      const int S = (w * 8 + ln * 2 + (kq >> 1)) * 16 + n;
      *(half4*)((_Float16*)hbw + S * 8 + 4 * (kq & 1)) = hv;
    }
    __syncthreads();   // one barrier per step
  }

  // ---- output 1: h_last (1,B,H) fp32 at out+4096 (final h in buffer 0) ----
  const half8* hf = hb8;   // buffer 0 (T even)
  #pragma unroll
  for (int u = 0; u < 2; ++u) {
    const int ri = tid + u * 512;
    const int k8 = ri >> 4, nb = ri & 15;
    const half8 v = hf[k8 * 16 + nb];
    float* dst = out + 4096 + (g * 16 + nb) * H_ + k8 * 8;
    #pragma unroll
    for (int e = 0; e < 8; ++e) dst[e] = (float)v[e];
  }
  // ---- output 0: FC (reuse wlds as fp32 [16][513]) ----
  __syncthreads();
  float* wfcf = (float*)wlds;
  #pragma unroll
  for (int u = 0; u < 16; ++u) {
    const int idx = tid + u * 512;
    wfcf[(idx >> 9) * 513 + (idx & 511)] = W_fc[idx];
  }
  __syncthreads();
  if (tid < 256) {
    const int bl = tid >> 4, o = tid & 15;
    float s = 0.f;
    #pragma unroll 8
    for (int k8 = 0; k8 < 64; ++k8) {
      const half8 v = hf[k8 * 16 + bl];
      #pragma unroll
      for (int e = 0; e < 8; ++e) s += (float)v[e] * wfcf[o * 513 + k8 * 8 + e];
    }
    out[(g * 16 + bl) * 16 + o] = s + b_fc[o];
  }
}

extern "C" void kernel_launch(void* const* d_in, const int* in_sizes, int n_in,
                              void* d_out, int out_size, void* d_ws, size_t ws_size,
                              hipStream_t stream) {
  const float* x    = (const float*)d_in[0];
  const float* h0   = (const float*)d_in[1];
  const float* W_ih = (const float*)d_in[2];
  const float* W_hh = (const float*)d_in[3];
  const float* b_ih = (const float*)d_in[4];
  const float* b_hh = (const float*)d_in[5];
  const float* W_fc = (const float*)d_in[6];
  const float* b_fc = (const float*)d_in[7];
  float* out = (float*)d_out;

  _Float16* xp = (_Float16*)d_ws;   // 134 MB f16 workspace

  xp_prepass<<<dim3(512), dim3(256), 0, stream>>>(x, W_ih, b_ih, b_hh, xp);
  rnn_persist<<<dim3(16), dim3(512), 0, stream>>>(h0, W_hh, W_fc, b_fc, out, xp);
}